// Round 14
// baseline (164.067 us; speedup 1.0000x reference)
//
#include <hip/hip_runtime.h>
#include <hip/hip_bf16.h>
#include <cstdint>
#include <cstddef>

#define L_SEQ 2048
#define BATCH 2
#define DM 1024
#define NH 16
#define DK 64
#define QKV_N 3072       // 3*DM (logical GEMM output width)
#define QK_N 2048        // packed q|k buffer width (V lives in vtb)
#define NX (4096 * 1024) // X element count
#define NW (3072 * 1024) // W element count

typedef short short8_t __attribute__((ext_vector_type(8)));
typedef short short4_t __attribute__((ext_vector_type(4)));
typedef float f32x4 __attribute__((ext_vector_type(4)));

#define MFMA32(a, b, c) __builtin_amdgcn_mfma_f32_16x16x32_bf16(a, b, c, 0, 0, 0)
#define MFMA16(a, b, c) __builtin_amdgcn_mfma_f32_16x16x16bf16_1k(a, b, c, 0, 0, 0)
// bare v_exp_f32 (2^x). exp2f() is an OCML libm call -- R10 regression.
#define EXP2(x) __builtin_amdgcn_exp2f(x)

// 2x fp32 -> packed bf16 pair (v_cvt_pk_bf16_f32 on gfx950), RNE.
static __device__ __forceinline__ unsigned pk2(float a, float b) {
  __hip_bfloat162 h = __float22bfloat162_rn(make_float2(a, b));
  union { __hip_bfloat162 h; unsigned u; } v;
  v.h = h;
  return v.u;
}

// async global->LDS, 16B per lane. LDS dest = wave-uniform base + lane*16.
static __device__ __forceinline__ void async_copy16(const unsigned short* g,
                                                    unsigned short* l) {
  __builtin_amdgcn_global_load_lds(
      (const __attribute__((address_space(1))) unsigned int*)g,
      (__attribute__((address_space(3))) unsigned int*)l, 16, 0, 0);
}

// ---------------------------------------------------------------------------
// fp32 -> bf16 cast of X and W into one contiguous bf16 buffer.
// ---------------------------------------------------------------------------
__global__ __launch_bounds__(256) void cast_kernel(
    const float* __restrict__ X, const float* __restrict__ W,
    unsigned short* __restrict__ dst) {
  const int e = (blockIdx.x * 256 + threadIdx.x) * 8;
  const float* src = (e < NX) ? &X[e] : &W[e - NX];
  const float4 v0 = *(const float4*)src;
  const float4 v1 = *(const float4*)(src + 4);
  union { short8_t s8; unsigned u[4]; } o;
  o.u[0] = pk2(v0.x, v0.y);
  o.u[1] = pk2(v0.z, v0.w);
  o.u[2] = pk2(v1.x, v1.y);
  o.u[3] = pk2(v1.z, v1.w);
  *(short8_t*)&dst[e] = o.s8;
}

// ---------------------------------------------------------------------------
// bf16 MFMA QKV GEMM, fused RoPE + q-scale epilogue, bf16 output.
// R10 (kept): bijective XCD swizzle + pair-interleaved qkb stores.
// qkb [4096][2048]: rows (l*2+b), cols h*128 + {q:0|k:64} + perm(d).
// vtb [b][h][64 d][2048 j]: V stored TRANSPOSED (j = seq pos).
// q-scale = 0.125 * log2(e): attention computes softmax in exp2-space.
// NOTE: no setprio here -- m190 measured T5 null/negative on lockstep GEMM.
// ---------------------------------------------------------------------------
__global__ __launch_bounds__(256) void qkv_gemm_bf16(
    const unsigned short* __restrict__ Xb, const unsigned short* __restrict__ Wb,
    unsigned short* __restrict__ qkb, unsigned short* __restrict__ vtb) {
  __shared__ __align__(16) unsigned short As[2][128 * 32];  // [buf][m][k]
  __shared__ __align__(16) unsigned short Bs[2][128 * 32];  // [buf][n][k]
  const int t = threadIdx.x;
  const int w = t >> 6;
  const int lane = t & 63;
  const int L16 = lane & 15;
  const int quad = lane >> 4;
  // XCD-aware bijective swizzle: hw id -> logical tile id (768 = 96*8).
  const int hid = blockIdx.y * 24 + blockIdx.x;
  const int id = (hid & 7) * 96 + (hid >> 3);
  const int n0 = (id % 24) * 128;
  const int m0 = (id / 24) * 128;
  const int wm = w & 1;
  const int wn = w >> 1;

  const int c0 = w * 128 + lane;
  const int c1 = c0 + 64;
  const unsigned short* gA0 = Xb + (size_t)(m0 + (c0 >> 2)) * 1024 + (c0 & 3) * 8;
  const unsigned short* gA1 = Xb + (size_t)(m0 + (c1 >> 2)) * 1024 + (c1 & 3) * 8;
  const unsigned short* gB0 = Wb + (size_t)(n0 + (c0 >> 2)) * 1024 + (c0 & 3) * 8;
  const unsigned short* gB1 = Wb + (size_t)(n0 + (c1 >> 2)) * 1024 + (c1 & 3) * 8;

  f32x4 acc[4][4];
#pragma unroll
  for (int i = 0; i < 4; ++i)
#pragma unroll
    for (int j = 0; j < 4; ++j) acc[i][j] = (f32x4){0.f, 0.f, 0.f, 0.f};

  // prologue: stage tile 0 into buf 0
  async_copy16(gA0, &As[0][w * 1024]);
  async_copy16(gA1, &As[0][w * 1024 + 512]);
  async_copy16(gB0, &Bs[0][w * 1024]);
  async_copy16(gB1, &Bs[0][w * 1024 + 512]);

#define GBODY(K0, BUF)                                                        \
  {                                                                           \
    __syncthreads(); /* drains DMA(K0); prior readers of buf done */          \
    if ((K0) + 32 < 1024) {                                                   \
      async_copy16(gA0 + (K0) + 32, &As[(BUF) ^ 1][w * 1024]);                \
      async_copy16(gA1 + (K0) + 32, &As[(BUF) ^ 1][w * 1024 + 512]);          \
      async_copy16(gB0 + (K0) + 32, &Bs[(BUF) ^ 1][w * 1024]);                \
      async_copy16(gB1 + (K0) + 32, &Bs[(BUF) ^ 1][w * 1024 + 512]);          \
    }                                                                         \
    short8_t af[4], bfr[4];                                                   \
    _Pragma("unroll") for (int mt = 0; mt < 4; ++mt)                          \
        af[mt] = *(const short8_t*)                                           \
            &As[BUF][(wm * 64 + mt * 16 + L16) * 32 + quad * 8];              \
    _Pragma("unroll") for (int nt = 0; nt < 4; ++nt)                          \
        bfr[nt] = *(const short8_t*)                                          \
            &Bs[BUF][(wn * 64 + nt * 16 + L16) * 32 + quad * 8];              \
    _Pragma("unroll") for (int mt = 0; mt < 4; ++mt)                          \
        _Pragma("unroll") for (int nt = 0; nt < 4; ++nt)                      \
            acc[mt][nt] = MFMA32(af[mt], bfr[nt], acc[mt][nt]);               \
  }

  for (int k0 = 0; k0 < 1024; k0 += 64) {
    GBODY(k0, 0)
    GBODY(k0 + 32, 1)
  }

  const int chunk = (n0 >> 6) + wn;  // 64-col chunk in logical qkv order
  const int h = chunk / 3;
  const int type = chunk % 3;        // 0=q, 1=k, 2=v
  if (type == 2) {
    // V^T store: vtb[((b*16+h)*64 + d)*2048 + j].
#pragma unroll
    for (int mt = 0; mt < 4; ++mt) {
      const int mbase = m0 + wm * 64 + mt * 16 + quad * 4;  // even
      const int lb = mbase >> 1;
#pragma unroll
      for (int nt = 0; nt < 4; ++nt) {
        const int d = L16 + nt * 16;
        const size_t r0 = ((size_t)(h * 64 + d)) * 2048 + lb;           // b=0
        const size_t r1 = ((size_t)((16 + h) * 64 + d)) * 2048 + lb;    // b=1
        *(unsigned*)&vtb[r0] = pk2(acc[mt][nt][0], acc[mt][nt][2]);
        *(unsigned*)&vtb[r1] = pk2(acc[mt][nt][1], acc[mt][nt][3]);
      }
    }
  } else {
    // q gets 0.125*log2(e) so attention can use bare v_exp (exp2-space).
    // Pair-interleaved store: u32 covers logical cols (L16, L16+16) at
    // physical 2*L16, and (L16+32, L16+48) at 32+2*L16.
    const float qs = (type == 0) ? 0.18033688011112042f : 1.0f;
    const int cbase = h * 128 + type * 64 + L16 * 2;
    const float theta = exp2f(-(float)L16 * 0.8304820237218405f);
#pragma unroll
    for (int mt = 0; mt < 4; ++mt) {
      const int mbase = m0 + wm * 64 + mt * 16 + quad * 4;  // even
      const int lb = mbase >> 1;
      float sv[2], cv[2];
      __sincosf((float)lb * theta, &sv[0], &cv[0]);
      __sincosf((float)(lb + 1) * theta, &sv[1], &cv[1]);
#pragma unroll
      for (int reg = 0; reg < 4; ++reg) {
        const int li = reg >> 1;
        const float v0 = acc[mt][0][reg], v1 = acc[mt][1][reg];
        const float r0 = v0 * cv[li] - v1 * sv[li];
        const float r1 = v1 * cv[li] + v0 * sv[li];
        const size_t r = (size_t)(mbase + reg) * QK_N + cbase;
        *(unsigned*)&qkb[r]      = pk2(r0 * qs, r1 * qs);
        *(unsigned*)&qkb[r + 32] = pk2(acc[mt][2][reg] * qs,
                                       acc[mt][3][reg] * qs);
      }
    }
  }
}

// ---------------------------------------------------------------------------
// bf16 MFMA attention -- R14: q-split x2 on the LEAN body (TLP fix).
//   R13 post-mortem: ones-row MFMA matched counters (VALU 40->35) but HURT
//   (+2.4us) -> VALU utilization not binding; latency + 2-waves/SIMD is.
//   Grid 512 = exactly 2 blocks/CU (grid-capped TLP). R3's q-split failed on
//   the OLD body (V reg-transpose + LDS writes doubled with blocks); the
//   lean body (R8+) stages via 4 DMAs only -> q-split now duplicates only
//   slack L2 traffic, needs NO merge. 64 q-rows/block, 1 m-tile/wave,
//   grid (32,32) = 1024 blocks = 4 blocks/CU = 4 waves/SIMD.
//   XCD remap extended bijectively: 8 XCDs x 4 bh x 32 l0 = 1024.
// Kept: R12 remap principle, merged QK->exp->PV per-nt loop, scalar l_part
// (R13's l_acc reverted), setprio, XOR swizzles, vtb V^T.
// ---------------------------------------------------------------------------
__global__ __launch_bounds__(256, 4) void attn_mfma_kernel(
    const unsigned short* __restrict__ qkb,
    const unsigned short* __restrict__ vtb, float* __restrict__ out) {
  __shared__ __align__(16) unsigned short Ks[2][4096];  // [buf][j*64 + swz(k)]
  __shared__ __align__(16) unsigned short Vs[2][4096];  // [buf][d*64 + swz(j)]

  const int t = threadIdx.x;
  const int w = t >> 6;
  const int lane = t & 63;
  const int L16 = lane & 15;
  const int quad = lane >> 4;
  // XCD-aware remap: blocks sharing a (b,h) K/V panel land on one XCD.
  const int hid = blockIdx.y * 32 + blockIdx.x;   // grid (32, 32), 1024 blocks
  const int bh = (hid & 7) * 4 + ((hid >> 3) & 3);
  const int l0 = (hid >> 5) * 64;
  const int b = bh & 1;
  const int h = bh >> 1;
  const int vh = b * 16 + h;

  const f32x4 z4 = {0.f, 0.f, 0.f, 0.f};

  // ---- hoisted Q B-fragments (1 m-tile: 16 q-rows per wave) ----
  short8_t bq[2];
#pragma unroll
  for (int kc = 0; kc < 2; ++kc)
    bq[kc] = *(const short8_t*)
        &qkb[((size_t)((l0 + w * 16 + L16) * 2 + b)) * QK_N +
             h * 128 + kc * 32 + quad * 8];

  f32x4 oc[4];
  float l_part = 0.f;
#pragma unroll
  for (int dt = 0; dt < 4; ++dt) oc[dt] = z4;

  // ---- K async-copy state (XOR-swizzled source column) ----
  const int kr0 = w * 8 + (lane >> 3);
  const int kcs = ((lane & 7) ^ (lane >> 3)) * 8;
  const unsigned short* gK0 =
      qkb + (size_t)(kr0 * 2 + b) * QK_N + h * 128 + 64 + kcs;
  const unsigned short* gK1 = gK0 + (size_t)64 * QK_N;
  const size_t kstep = (size_t)128 * QK_N;

  // ---- V async-copy state: lane covers d = w*8 + (lane>>3) (+32 for gV1),
  //      source j-group inverse-swizzled so LDS image = V^T[d][j ^ swz(d)].
  const unsigned short* gV0 =
      vtb + ((size_t)(vh * 64 + w * 8 + (lane >> 3))) * 2048 +
      (((lane & 7) ^ (lane >> 3)) << 3);
  const unsigned short* gV1 = gV0 + (size_t)32 * 2048;

  // prologue: stage tile 0 into buf 0
  async_copy16(gK0, &Ks[0][w * 512]);
  async_copy16(gK1, &Ks[0][w * 512 + 2048]);
  async_copy16(gV0, &Vs[0][w * 512]);
  async_copy16(gV1, &Vs[0][w * 512 + 2048]);

  const int rsw = (L16 & 7);
  const int vswz = (L16 & 7) << 3;

#define ABODY(KT, BUF)                                                        \
  {                                                                           \
    __syncthreads(); /* drains DMA(BUF); prior readers of BUF^1 done */       \
    if ((KT) + 1 < 32) {                                                      \
      async_copy16(gK0 + (size_t)((KT) + 1) * kstep, &Ks[(BUF) ^ 1][w * 512]);\
      async_copy16(gK1 + (size_t)((KT) + 1) * kstep,                          \
                   &Ks[(BUF) ^ 1][w * 512 + 2048]);                           \
      async_copy16(gV0 + ((KT) + 1) * 64, &Vs[(BUF) ^ 1][w * 512]);           \
      async_copy16(gV1 + ((KT) + 1) * 64, &Vs[(BUF) ^ 1][w * 512 + 2048]);    \
    }                                                                         \
    __builtin_amdgcn_s_setprio(1);                                            \
    _Pragma("unroll") for (int nt = 0; nt < 4; ++nt) {                        \
      const short8_t ak0 = *(const short8_t*)                                 \
          &Ks[BUF][(nt * 16 + L16) * 64 + (quad ^ rsw) * 8];                  \
      const short8_t ak1 = *(const short8_t*)                                 \
          &Ks[BUF][(nt * 16 + L16) * 64 + ((quad + 4) ^ rsw) * 8];            \
      f32x4 t0 = MFMA32(ak0, bq[0], z4);                                      \
      const f32x4 s0v = MFMA32(ak1, bq[1], t0);                               \
      float p0 = EXP2(s0v[0]), p1 = EXP2(s0v[1]);                             \
      float p2 = EXP2(s0v[2]), p3 = EXP2(s0v[3]);                             \
      l_part += (p0 + p1) + (p2 + p3);                                        \
      union { short4_t s4; unsigned u[2]; } pu0;                              \
      pu0.u[0] = pk2(p0, p1);                                                 \
      pu0.u[1] = pk2(p2, p3);                                                 \
      _Pragma("unroll") for (int dt = 0; dt < 4; ++dt) {                      \
        const short4_t vf = *(const short4_t*)                                \
            &Vs[BUF][(dt * 16 + L16) * 64 + ((nt * 16 + quad * 4) ^ vswz)];   \
        oc[dt] = MFMA16(vf, pu0.s4, oc[dt]);                                  \
      }                                                                       \
    }                                                                         \
    __builtin_amdgcn_s_setprio(0);                                            \
  }

  for (int kt = 0; kt < 32; kt += 2) {
    ABODY(kt, 0)
    ABODY(kt + 1, 1)
  }

  // ---- final row-sum reduction + epilogue ----
  {
    float l = l_part;
    l += __shfl_xor(l, 16);
    l += __shfl_xor(l, 32);
    const float inv = 1.f / l;
    const int qrow = l0 + w * 16 + L16;
    const size_t rbase = ((size_t)(qrow * 2 + b)) * DM + h * DK;
#pragma unroll
    for (int dt = 0; dt < 4; ++dt) {
      *(float4*)&out[rbase + dt * 16 + quad * 4] =
          make_float4(oc[dt][0] * inv, oc[dt][1] * inv,
                      oc[dt][2] * inv, oc[dt][3] * inv);
    }
  }
}

// ---------------------------------------------------------------------------
extern "C" void kernel_launch(void* const* d_in, const int* in_sizes, int n_in,
                              void* d_out, int out_size, void* d_ws,
                              size_t ws_size, hipStream_t stream) {
  const float* x = (const float*)d_in[0];
  const float* w = (const float*)d_in[1];
  float* out = (float*)d_out;
  unsigned short* bf = (unsigned short*)d_ws;          // Xb (8MB) + Wb (6MB)
  unsigned short* Xb = bf;
  unsigned short* Wb = bf + NX;
  unsigned short* qkb =
      (unsigned short*)((char*)d_ws + (16u << 20));    // 16 MB bf16 q|k
  unsigned short* vtb =
      (unsigned short*)((char*)d_ws + (32u << 20));    // 8 MB bf16 V^T

  cast_kernel<<<(NX + NW) / (256 * 8), 256, 0, stream>>>(x, w, bf);
  qkv_gemm_bf16<<<dim3(QKV_N / 128, (L_SEQ * BATCH) / 128), 256, 0, stream>>>(
      Xb, Wb, qkb, vtb);
  attn_mfma_kernel<<<dim3(L_SEQ / 64, NH * BATCH), 256, 0, stream>>>(qkb, vtb,
                                                                     out);
}

// Round 15
// 156.315 us; speedup vs baseline: 1.0496x; 1.0496x over previous
//
#include <hip/hip_runtime.h>
#include <hip/hip_bf16.h>
#include <cstdint>
#include <cstddef>

#define L_SEQ 2048
#define BATCH 2
#define DM 1024
#define NH 16
#define DK 64
#define QKV_N 3072       // 3*DM (logical GEMM output width)
#define QK_N 2048        // packed q|k buffer width (V lives in vtb)
#define NX (4096 * 1024) // X element count
#define NW (3072 * 1024) // W element count

typedef short short8_t __attribute__((ext_vector_type(8)));
typedef short short4_t __attribute__((ext_vector_type(4)));
typedef float f32x4 __attribute__((ext_vector_type(4)));

#define MFMA32(a, b, c) __builtin_amdgcn_mfma_f32_16x16x32_bf16(a, b, c, 0, 0, 0)
#define MFMA16(a, b, c) __builtin_amdgcn_mfma_f32_16x16x16bf16_1k(a, b, c, 0, 0, 0)
// bare v_exp_f32 (2^x). exp2f() is an OCML libm call -- R10 regression.
#define EXP2(x) __builtin_amdgcn_exp2f(x)

// 2x fp32 -> packed bf16 pair (v_cvt_pk_bf16_f32 on gfx950), RNE.
static __device__ __forceinline__ unsigned pk2(float a, float b) {
  __hip_bfloat162 h = __float22bfloat162_rn(make_float2(a, b));
  union { __hip_bfloat162 h; unsigned u; } v;
  v.h = h;
  return v.u;
}

// async global->LDS, 16B per lane. LDS dest = wave-uniform base + lane*16.
static __device__ __forceinline__ void async_copy16(const unsigned short* g,
                                                    unsigned short* l) {
  __builtin_amdgcn_global_load_lds(
      (const __attribute__((address_space(1))) unsigned int*)g,
      (__attribute__((address_space(3))) unsigned int*)l, 16, 0, 0);
}

// ---------------------------------------------------------------------------
// fp32 -> bf16 cast of X and W into one contiguous bf16 buffer.
// ---------------------------------------------------------------------------
__global__ __launch_bounds__(256) void cast_kernel(
    const float* __restrict__ X, const float* __restrict__ W,
    unsigned short* __restrict__ dst) {
  const int e = (blockIdx.x * 256 + threadIdx.x) * 8;
  const float* src = (e < NX) ? &X[e] : &W[e - NX];
  const float4 v0 = *(const float4*)src;
  const float4 v1 = *(const float4*)(src + 4);
  union { short8_t s8; unsigned u[4]; } o;
  o.u[0] = pk2(v0.x, v0.y);
  o.u[1] = pk2(v0.z, v0.w);
  o.u[2] = pk2(v1.x, v1.y);
  o.u[3] = pk2(v1.z, v1.w);
  *(short8_t*)&dst[e] = o.s8;
}

// ---------------------------------------------------------------------------
// bf16 MFMA QKV GEMM, fused RoPE + q-scale epilogue, bf16 output.
// R10 (kept): bijective XCD swizzle + pair-interleaved qkb stores.
// qkb [4096][2048]: rows (l*2+b), cols h*128 + {q:0|k:64} + perm(d).
// vtb [b][h][64 d][2048 j]: V stored TRANSPOSED (j = seq pos).
// q-scale = 0.125 * log2(e): attention computes softmax in exp2-space.
// NOTE: no setprio here -- m190 measured T5 null/negative on lockstep GEMM.
// ---------------------------------------------------------------------------
__global__ __launch_bounds__(256) void qkv_gemm_bf16(
    const unsigned short* __restrict__ Xb, const unsigned short* __restrict__ Wb,
    unsigned short* __restrict__ qkb, unsigned short* __restrict__ vtb) {
  __shared__ __align__(16) unsigned short As[2][128 * 32];  // [buf][m][k]
  __shared__ __align__(16) unsigned short Bs[2][128 * 32];  // [buf][n][k]
  const int t = threadIdx.x;
  const int w = t >> 6;
  const int lane = t & 63;
  const int L16 = lane & 15;
  const int quad = lane >> 4;
  // XCD-aware bijective swizzle: hw id -> logical tile id (768 = 96*8).
  const int hid = blockIdx.y * 24 + blockIdx.x;
  const int id = (hid & 7) * 96 + (hid >> 3);
  const int n0 = (id % 24) * 128;
  const int m0 = (id / 24) * 128;
  const int wm = w & 1;
  const int wn = w >> 1;

  const int c0 = w * 128 + lane;
  const int c1 = c0 + 64;
  const unsigned short* gA0 = Xb + (size_t)(m0 + (c0 >> 2)) * 1024 + (c0 & 3) * 8;
  const unsigned short* gA1 = Xb + (size_t)(m0 + (c1 >> 2)) * 1024 + (c1 & 3) * 8;
  const unsigned short* gB0 = Wb + (size_t)(n0 + (c0 >> 2)) * 1024 + (c0 & 3) * 8;
  const unsigned short* gB1 = Wb + (size_t)(n0 + (c1 >> 2)) * 1024 + (c1 & 3) * 8;

  f32x4 acc[4][4];
#pragma unroll
  for (int i = 0; i < 4; ++i)
#pragma unroll
    for (int j = 0; j < 4; ++j) acc[i][j] = (f32x4){0.f, 0.f, 0.f, 0.f};

  // prologue: stage tile 0 into buf 0
  async_copy16(gA0, &As[0][w * 1024]);
  async_copy16(gA1, &As[0][w * 1024 + 512]);
  async_copy16(gB0, &Bs[0][w * 1024]);
  async_copy16(gB1, &Bs[0][w * 1024 + 512]);

#define GBODY(K0, BUF)                                                        \
  {                                                                           \
    __syncthreads(); /* drains DMA(K0); prior readers of buf done */          \
    if ((K0) + 32 < 1024) {                                                   \
      async_copy16(gA0 + (K0) + 32, &As[(BUF) ^ 1][w * 1024]);                \
      async_copy16(gA1 + (K0) + 32, &As[(BUF) ^ 1][w * 1024 + 512]);          \
      async_copy16(gB0 + (K0) + 32, &Bs[(BUF) ^ 1][w * 1024]);                \
      async_copy16(gB1 + (K0) + 32, &Bs[(BUF) ^ 1][w * 1024 + 512]);          \
    }                                                                         \
    short8_t af[4], bfr[4];                                                   \
    _Pragma("unroll") for (int mt = 0; mt < 4; ++mt)                          \
        af[mt] = *(const short8_t*)                                           \
            &As[BUF][(wm * 64 + mt * 16 + L16) * 32 + quad * 8];              \
    _Pragma("unroll") for (int nt = 0; nt < 4; ++nt)                          \
        bfr[nt] = *(const short8_t*)                                          \
            &Bs[BUF][(wn * 64 + nt * 16 + L16) * 32 + quad * 8];              \
    _Pragma("unroll") for (int mt = 0; mt < 4; ++mt)                          \
        _Pragma("unroll") for (int nt = 0; nt < 4; ++nt)                      \
            acc[mt][nt] = MFMA32(af[mt], bfr[nt], acc[mt][nt]);               \
  }

  for (int k0 = 0; k0 < 1024; k0 += 64) {
    GBODY(k0, 0)
    GBODY(k0 + 32, 1)
  }

  const int chunk = (n0 >> 6) + wn;  // 64-col chunk in logical qkv order
  const int h = chunk / 3;
  const int type = chunk % 3;        // 0=q, 1=k, 2=v
  if (type == 2) {
    // V^T store: vtb[((b*16+h)*64 + d)*2048 + j].
#pragma unroll
    for (int mt = 0; mt < 4; ++mt) {
      const int mbase = m0 + wm * 64 + mt * 16 + quad * 4;  // even
      const int lb = mbase >> 1;
#pragma unroll
      for (int nt = 0; nt < 4; ++nt) {
        const int d = L16 + nt * 16;
        const size_t r0 = ((size_t)(h * 64 + d)) * 2048 + lb;           // b=0
        const size_t r1 = ((size_t)((16 + h) * 64 + d)) * 2048 + lb;    // b=1
        *(unsigned*)&vtb[r0] = pk2(acc[mt][nt][0], acc[mt][nt][2]);
        *(unsigned*)&vtb[r1] = pk2(acc[mt][nt][1], acc[mt][nt][3]);
      }
    }
  } else {
    // q gets 0.125*log2(e) so attention can use bare v_exp (exp2-space).
    // Pair-interleaved store: u32 covers logical cols (L16, L16+16) at
    // physical 2*L16, and (L16+32, L16+48) at 32+2*L16.
    const float qs = (type == 0) ? 0.18033688011112042f : 1.0f;
    const int cbase = h * 128 + type * 64 + L16 * 2;
    const float theta = exp2f(-(float)L16 * 0.8304820237218405f);
#pragma unroll
    for (int mt = 0; mt < 4; ++mt) {
      const int mbase = m0 + wm * 64 + mt * 16 + quad * 4;  // even
      const int lb = mbase >> 1;
      float sv[2], cv[2];
      __sincosf((float)lb * theta, &sv[0], &cv[0]);
      __sincosf((float)(lb + 1) * theta, &sv[1], &cv[1]);
#pragma unroll
      for (int reg = 0; reg < 4; ++reg) {
        const int li = reg >> 1;
        const float v0 = acc[mt][0][reg], v1 = acc[mt][1][reg];
        const float r0 = v0 * cv[li] - v1 * sv[li];
        const float r1 = v1 * cv[li] + v0 * sv[li];
        const size_t r = (size_t)(mbase + reg) * QK_N + cbase;
        *(unsigned*)&qkb[r]      = pk2(r0 * qs, r1 * qs);
        *(unsigned*)&qkb[r + 32] = pk2(acc[mt][2][reg] * qs,
                                       acc[mt][3][reg] * qs);
      }
    }
  }
}

// ---------------------------------------------------------------------------
// bf16 MFMA attention -- R15: T4 counted-vmcnt 3-buffer pipeline.
//   Triangulation: R9 (fewer barriers: null), R13 (VALU offload: hurt),
//   R14 (2x TLP: null) -> the residual ~50% step-period slack is the
//   full vmcnt(0) drain + 2-deep lockstep pipeline. Fix: stage 2 tiles
//   ahead into 3 LDS buffers; per step `s_waitcnt vmcnt(4)` (drains only
//   the tile about to be computed; next tile's 4 DMAs stay in flight
//   ACROSS the barrier) + raw s_barrier, replacing __syncthreads' drain.
//   Hazards: RAW -- own stage(kt) drained by vmcnt(4) pre-barrier, all
//   waves' writes visible post-barrier. WAR -- stage(kt+2) hits
//   buf((kt-1)%3), whose reads were register-consumed (lgkmcnt) before
//   this barrier; issue is post-barrier. Compiler reorder blocked by
//   "memory" clobber. LDS 48KB, 2 blocks/CU unchanged at lb(256,2).
// Base = R12/R13-base (best total 156.8): XCD remap, merged per-nt loop,
// scalar l_part, setprio, XOR swizzles, vtb V^T.
// ---------------------------------------------------------------------------
__global__ __launch_bounds__(256, 2) void attn_mfma_kernel(
    const unsigned short* __restrict__ qkb,
    const unsigned short* __restrict__ vtb, float* __restrict__ out) {
  __shared__ __align__(16) unsigned short Ks[3][4096];  // [buf][j*64 + swz(k)]
  __shared__ __align__(16) unsigned short Vs[3][4096];  // [buf][d*64 + swz(j)]

  const int t = threadIdx.x;
  const int w = t >> 6;
  const int lane = t & 63;
  const int L16 = lane & 15;
  const int quad = lane >> 4;
  // XCD-aware remap: blocks sharing a (b,h) K/V panel land on one XCD.
  const int hid = blockIdx.y * 16 + blockIdx.x;   // grid (16, 32), 512 blocks
  const int bh = (hid & 7) * 4 + ((hid >> 3) & 3);
  const int l0 = (hid >> 5) * 128;
  const int b = bh & 1;
  const int h = bh >> 1;
  const int vh = b * 16 + h;

  const f32x4 z4 = {0.f, 0.f, 0.f, 0.f};

  // ---- hoisted Q B-fragments for 2 m-tiles ----
  short8_t bq[2][2];
#pragma unroll
  for (int mt = 0; mt < 2; ++mt)
#pragma unroll
    for (int kc = 0; kc < 2; ++kc)
      bq[mt][kc] = *(const short8_t*)
          &qkb[((size_t)((l0 + w * 32 + mt * 16 + L16) * 2 + b)) * QK_N +
               h * 128 + kc * 32 + quad * 8];

  f32x4 oc[2][4];
  float l_part[2] = {0.f, 0.f};
#pragma unroll
  for (int mt = 0; mt < 2; ++mt)
#pragma unroll
    for (int dt = 0; dt < 4; ++dt) oc[mt][dt] = z4;

  // ---- K async-copy state (XOR-swizzled source column) ----
  const int kr0 = w * 8 + (lane >> 3);
  const int kcs = ((lane & 7) ^ (lane >> 3)) * 8;
  const unsigned short* gK0 =
      qkb + (size_t)(kr0 * 2 + b) * QK_N + h * 128 + 64 + kcs;
  const unsigned short* gK1 = gK0 + (size_t)64 * QK_N;
  const size_t kstep = (size_t)128 * QK_N;

  // ---- V async-copy state: lane covers d = w*8 + (lane>>3) (+32 for gV1),
  //      source j-group inverse-swizzled so LDS image = V^T[d][j ^ swz(d)].
  const unsigned short* gV0 =
      vtb + ((size_t)(vh * 64 + w * 8 + (lane >> 3))) * 2048 +
      (((lane & 7) ^ (lane >> 3)) << 3);
  const unsigned short* gV1 = gV0 + (size_t)32 * 2048;

#define STAGE(KT, B)                                                          \
  {                                                                           \
    async_copy16(gK0 + (size_t)(KT) * kstep, &Ks[B][w * 512]);                \
    async_copy16(gK1 + (size_t)(KT) * kstep, &Ks[B][w * 512 + 2048]);         \
    async_copy16(gV0 + (KT) * 64, &Vs[B][w * 512]);                           \
    async_copy16(gV1 + (KT) * 64, &Vs[B][w * 512 + 2048]);                    \
  }

  // prologue: stage tiles 0,1 into bufs 0,1 (8 DMAs outstanding)
  STAGE(0, 0)
  STAGE(1, 1)

  const int rsw = (L16 & 7);
  const int vswz = (L16 & 7) << 3;

  int cur = 0;
  for (int kt = 0; kt < 32; ++kt) {
    // counted drain: stage(kt) done; stage(kt+1)'s 4 DMAs stay in flight.
    asm volatile("s_waitcnt vmcnt(4)\n\ts_barrier" ::: "memory");
    if (kt + 2 < 32) {
      const int nb = (cur + 2 >= 3) ? cur - 1 : cur + 2;
      STAGE(kt + 2, nb)
    }
    __builtin_amdgcn_s_setprio(1);
#pragma unroll
    for (int nt = 0; nt < 4; ++nt) {
      const short8_t ak0 = *(const short8_t*)
          &Ks[cur][(nt * 16 + L16) * 64 + (quad ^ rsw) * 8];
      const short8_t ak1 = *(const short8_t*)
          &Ks[cur][(nt * 16 + L16) * 64 + ((quad + 4) ^ rsw) * 8];
      f32x4 t0 = MFMA32(ak0, bq[0][0], z4);
      const f32x4 s0v = MFMA32(ak1, bq[0][1], t0);
      f32x4 t1 = MFMA32(ak0, bq[1][0], z4);
      const f32x4 s1v = MFMA32(ak1, bq[1][1], t1);
      float p0 = EXP2(s0v[0]), p1 = EXP2(s0v[1]);
      float p2 = EXP2(s0v[2]), p3 = EXP2(s0v[3]);
      l_part[0] += (p0 + p1) + (p2 + p3);
      union { short4_t s4; unsigned u[2]; } pu0;
      pu0.u[0] = pk2(p0, p1);
      pu0.u[1] = pk2(p2, p3);
      float q0 = EXP2(s1v[0]), q1 = EXP2(s1v[1]);
      float q2 = EXP2(s1v[2]), q3 = EXP2(s1v[3]);
      l_part[1] += (q0 + q1) + (q2 + q3);
      union { short4_t s4; unsigned u[2]; } pu1;
      pu1.u[0] = pk2(q0, q1);
      pu1.u[1] = pk2(q2, q3);
#pragma unroll
      for (int dt = 0; dt < 4; ++dt) {
        const short4_t vf = *(const short4_t*)
            &Vs[cur][(dt * 16 + L16) * 64 + ((nt * 16 + quad * 4) ^ vswz)];
        oc[0][dt] = MFMA16(vf, pu0.s4, oc[0][dt]);
        oc[1][dt] = MFMA16(vf, pu1.s4, oc[1][dt]);
      }
    }
    __builtin_amdgcn_s_setprio(0);
    cur = (cur == 2) ? 0 : cur + 1;
  }

  // ---- final row-sum reductions + epilogue ----
#pragma unroll
  for (int mt = 0; mt < 2; ++mt) {
    float l = l_part[mt];
    l += __shfl_xor(l, 16);
    l += __shfl_xor(l, 32);
    const float inv = 1.f / l;
    const int qrow = l0 + w * 32 + mt * 16 + L16;
    const size_t rbase = ((size_t)(qrow * 2 + b)) * DM + h * DK;
#pragma unroll
    for (int dt = 0; dt < 4; ++dt) {
      *(float4*)&out[rbase + dt * 16 + quad * 4] =
          make_float4(oc[mt][dt][0] * inv, oc[mt][dt][1] * inv,
                      oc[mt][dt][2] * inv, oc[mt][dt][3] * inv);
    }
  }
}

// ---------------------------------------------------------------------------
extern "C" void kernel_launch(void* const* d_in, const int* in_sizes, int n_in,
                              void* d_out, int out_size, void* d_ws,
                              size_t ws_size, hipStream_t stream) {
  const float* x = (const float*)d_in[0];
  const float* w = (const float*)d_in[1];
  float* out = (float*)d_out;
  unsigned short* bf = (unsigned short*)d_ws;          // Xb (8MB) + Wb (6MB)
  unsigned short* Xb = bf;
  unsigned short* Wb = bf + NX;
  unsigned short* qkb =
      (unsigned short*)((char*)d_ws + (16u << 20));    // 16 MB bf16 q|k
  unsigned short* vtb =
      (unsigned short*)((char*)d_ws + (32u << 20));    // 8 MB bf16 V^T

  cast_kernel<<<(NX + NW) / (256 * 8), 256, 0, stream>>>(x, w, bf);
  qkv_gemm_bf16<<<dim3(QKV_N / 128, (L_SEQ * BATCH) / 128), 256, 0, stream>>>(
      Xb, Wb, qkb, vtb);
  attn_mfma_kernel<<<dim3(L_SEQ / 128, NH * BATCH), 256, 0, stream>>>(qkb, vtb,
                                                                      out);
}